// Round 24
// baseline (228.836 us; speedup 1.0000x reference)
//
#include <hip/hip_runtime.h>
#include <hip/hip_bf16.h>

typedef float f32x4 __attribute__((ext_vector_type(4)));
typedef float f32x16 __attribute__((ext_vector_type(16)));
typedef long lx2 __attribute__((ext_vector_type(2)));
typedef long lx4 __attribute__((ext_vector_type(4)));
typedef int i32x8 __attribute__((ext_vector_type(8)));

#define B_N 1024
#define D_N 256
#define A_N 6
#define M_N 200000
#define K_N 16
#define H1_N 128
#define H2_N 64
#define NT32 6250       // 200000 / 32 (32-row tiles)
#define S_TILES 6       // prepass tiles per chunk (32-row tiles)
#define S_CHUNKS 64     // sample = 64*6*32 = 12288 rows
#define F_NC 128        // filter: m-chunk count (grid.x)
#define F_BY 8          // filter: b-groups of 128 cols -> 1024 blocks = 4/CU
#define CAP 1024        // per-b survivor capacity
#define SCL 0x7F7F7F7F  // E8M0 scale bytes = 127 -> 2^0 = 1.0 (unit scale)

// memn8 (RAW fp8 e4m3, NOT normalized) in 32x32-MFMA A-fragment UNITS:
// unit u of 32-row group g covers rows g*32..+31, cols u*32..+31 (1024 B).
// byte l*16 + h*8 + j = element (row = l&31, k_local = h*16 + (l>>5)*8 + j).
// Normalization moved to sim-space: sc = mfma_dot * rcpn[row], where
// rcpn[m] = 1/(||q(mem_m)|| + 1e-8) from the fp8 data itself (norm_kernel).
// C layout (verified): col = lane&31, row(i,lane) = (i&3)+8*(i>>2)+4*(lane>>5).

__device__ __forceinline__ float wred_sum(float v) {
#pragma unroll
  for (int o = 1; o < 64; o <<= 1) v += __shfl_xor(v, o, 64);
  return v;
}

__device__ __forceinline__ void topk_insert(float (&lst)[16], float v) {
  if (v <= lst[15]) return;
#pragma unroll
  for (int i = 0; i < 16; ++i) {
    bool gt = v > lst[i];
    float hi = gt ? v : lst[i];
    v = gt ? lst[i] : v;
    lst[i] = hi;
  }
}

__device__ __forceinline__ void load_lds16(const void* g, void* l) {
  __builtin_amdgcn_global_load_lds(
      (const __attribute__((address_space(1))) unsigned int*)g,
      (__attribute__((address_space(3))) unsigned int*)l, 16, 0, 0);
}

__device__ __forceinline__ int cvt2fp8(float a, float b) {
  return __builtin_amdgcn_cvt_pk_fp8_f32(a, b, 0, false);  // low 2 bytes
}

// ---------- fused: forward model (blocks 0..1023) + memcvt (blocks 1024+) ---
// memcvt is now a PURE streaming convert (no row reduce): load 1KB/row-instr,
// cvt raw f32->fp8, LDS transpose, 1KB fragment-unit stores.
__global__ __launch_bounds__(256) void prep_kernel(
    const float* __restrict__ mem, unsigned char* __restrict__ memn8,
    const float* __restrict__ z_t, const float* __restrict__ action,
    const float* __restrict__ z_t1, const float* __restrict__ sigma,
    const float* __restrict__ W1, const float* __restrict__ b1,
    const float* __restrict__ g1, const float* __restrict__ be1,
    const float* __restrict__ W2, const float* __restrict__ b2,
    const float* __restrict__ g2, const float* __restrict__ be2,
    const float* __restrict__ W3, const float* __restrict__ b3,
    float* __restrict__ out, unsigned char* __restrict__ z8) {
  __shared__ float s_inp[D_N + A_N];
  __shared__ float s_h1[H1_N];
  __shared__ float s_h2[H2_N];
  __shared__ float red[8];
  __shared__ char s8[32 * 264];  // 32 fp8 rows, 264 B pitch (bank rotate)
  const int t = threadIdx.x;
  const int w = t >> 6;
  const int l = t & 63;

  if (blockIdx.x >= B_N) {
    const int g32 = blockIdx.x - B_N;
    const float* src = mem + (size_t)g32 * 32 * D_N;
#pragma unroll
    for (int i = 0; i < 8; ++i) {
      const int r = i * 4 + w;  // wave-uniform row
      const f32x4 v = *(const f32x4*)(src + (size_t)r * D_N + l * 4);
      int p01 = cvt2fp8(v[0], v[1]);
      int p23 = cvt2fp8(v[2], v[3]);
      unsigned int four = (p01 & 0xffff) | ((unsigned)(p23 & 0xffff) << 16);
      *(unsigned int*)(s8 + r * 264 + l * 4) = four;
    }
    __syncthreads();
    char* dstb = (char*)memn8 + (size_t)g32 * 8192;  // 8 units x 1024 B
#pragma unroll
    for (int uu = 0; uu < 2; ++uu) {
      const int u = w * 2 + uu;  // wave-uniform unit
      const int koff = u * 32 + (l >> 5) * 8;
      long lo = *(const long*)(s8 + (l & 31) * 264 + koff);
      long hi = *(const long*)(s8 + (l & 31) * 264 + koff + 16);
      lx2 o; o[0] = lo; o[1] = hi;
      *(lx2*)(dstb + u * 1024 + l * 16) = o;
    }
    return;
  }

  // ---- forward model for sample b (z8 stays NORMALIZED fp8) ----
  const int bb = blockIdx.x;

  float zv = z_t[bb * D_N + t];
  s_inp[t] = zv;
  if (t < A_N) s_inp[D_N + t] = action[bb * A_N + t];

  float ss = wred_sum(zv * zv);
  if ((t & 63) == 0) red[w] = ss;
  __syncthreads();
  float tot = red[0] + red[1] + red[2] + red[3];
  float invz = 1.0f / (sqrtf(tot) + 1e-8f);
  if (t < 128) {
    int pk = cvt2fp8(s_inp[2 * t] * invz, s_inp[2 * t + 1] * invz);
    *(unsigned short*)(z8 + (size_t)bb * 256 + 2 * t) =
        (unsigned short)(pk & 0xffff);
  }

  float y1 = 0.0f;
  if (t < H1_N) {
    y1 = b1[t];
    for (int k = 0; k < D_N + A_N; ++k) y1 += s_inp[k] * W1[k * H1_N + t];
  }
  __syncthreads();
  float s1 = wred_sum(t < H1_N ? y1 : 0.0f);
  float q1 = wred_sum(t < H1_N ? y1 * y1 : 0.0f);
  if ((t & 63) == 0) { red[w] = s1; red[4 + w] = q1; }
  __syncthreads();
  float S1 = red[0] + red[1] + red[2] + red[3];
  float Q1 = red[4] + red[5] + red[6] + red[7];
  float mu1 = S1 / (float)H1_N;
  float var1 = Q1 / (float)H1_N - mu1 * mu1;
  float rs1 = rsqrtf(var1 + 1e-5f);
  if (t < H1_N) {
    float xn = (y1 - mu1) * rs1;
    s_h1[t] = fmaxf(0.0f, xn * g1[t] + be1[t]);
  }
  __syncthreads();

  float y2 = 0.0f;
  if (t < H2_N) {
    y2 = b2[t];
    for (int k = 0; k < H1_N; ++k) y2 += s_h1[k] * W2[k * H2_N + t];
  }
  __syncthreads();
  float s2 = wred_sum(t < H2_N ? y2 : 0.0f);
  float q2 = wred_sum(t < H2_N ? y2 * y2 : 0.0f);
  if ((t & 63) == 0) { red[w] = s2; red[4 + w] = q2; }
  __syncthreads();
  float S2 = red[0] + red[1] + red[2] + red[3];
  float Q2 = red[4] + red[5] + red[6] + red[7];
  float mu2 = S2 / (float)H2_N;
  float var2 = Q2 / (float)H2_N - mu2 * mu2;
  float rs2 = rsqrtf(var2 + 1e-5f);
  if (t < H2_N) {
    float xn = (y2 - mu2) * rs2;
    s_h2[t] = fmaxf(0.0f, xn * g2[t] + be2[t]);
  }
  __syncthreads();

  float zp = b3[t];
  for (int k = 0; k < H2_N; ++k) zp += s_h2[k] * W3[k * D_N + t];
  float d = zp - z_t1[bb * D_N + t];
  __syncthreads();
  float pe = wred_sum(d * d);
  if ((t & 63) == 0) red[w] = pe;
  __syncthreads();
  if (t == 0) {
    float PE = (red[0] + red[1] + red[2] + red[3]) / (float)D_N;
    out[B_N + bb] = PE;
    float s6 = 0.0f;
    for (int i = 0; i < A_N; ++i) s6 += sigma[bb * A_N + i];
    out[2 * B_N + bb] = s6 / (float)A_N;
  }
}

// ---------------- norm: rcpn[m] = 1/(||fp8 row m|| + 1e-8) ------------------
// Reads memn8 fragment units (16B/lane coalesced), decodes e4m3 in-register,
// LDS cross-wave reduce. 51.2 MB read -> ~15-25 us.
__global__ __launch_bounds__(256) void norm_kernel(
    const unsigned char* __restrict__ memn8, float* __restrict__ rcpn) {
  __shared__ float part[4][64];
  const int t = threadIdx.x;
  const int w = t >> 6;
  const int l = t & 63;
  const size_t g = blockIdx.x;
  const char* base = (const char*)memn8 + g * 8192 +
                     (size_t)(w * 2) * 1024 + l * 16;
  float ss = 0.f;
#pragma unroll
  for (int uu = 0; uu < 2; ++uu) {
    lx2 d = *(const lx2*)(base + uu * 1024);
#pragma unroll
    for (int h = 0; h < 2; ++h) {
      unsigned long long x = (unsigned long long)d[h];
#pragma unroll
      for (int b = 0; b < 8; ++b) {
        unsigned u = (unsigned)(x >> (8 * b)) & 0x7Fu;
        unsigned e = u >> 3, m = u & 7u;
        // e4m3: normal (8+m)*2^(e-10); denormal m*2^-9
        float val = e ? ldexpf((float)(8u + m), (int)e - 10)
                      : ldexpf((float)m, -9);
        ss += val * val;
      }
    }
  }
  part[w][l] = ss;
  __syncthreads();
  if (t < 32) {
    float tot = 0.f;
#pragma unroll
    for (int ww = 0; ww < 4; ++ww) tot += part[ww][t] + part[ww][t + 32];
    rcpn[g * 32 + t] = 1.0f / (sqrtf(tot) + 1e-8f);
  }
}

// ---------------- prepass: exact MX-fp8 top-16 over 12288-row sample --------
// sims = acc * rcpn[row] (bitwise identical to filter's gating math).
__global__ __launch_bounds__(512) void prepass_kernel(
    const unsigned char* __restrict__ memn8, const unsigned char* __restrict__ z8,
    const float* __restrict__ rcpn, float* __restrict__ tcand) {
  __shared__ char tile[8192];  // 8 units x 1024 B
  const int t = threadIdx.x;
  const int w = t >> 6;       // 0..7
  const int l = t & 63;
  const int c32 = l & 31;
  const int hi4 = (l >> 5) * 4;
  const int col = blockIdx.y * 256 + w * 32 + c32;

  lx4 zb[4];  // 32 VGPRs
#pragma unroll
  for (int g = 0; g < 4; ++g)
#pragma unroll
    for (int c = 0; c < 4; ++c)
      zb[g][c] = *(const long*)(z8 + (size_t)col * 256 + (4 * g + c) * 16 +
                                (l >> 5) * 8);

  float lst[16];
#pragma unroll
  for (int i = 0; i < 16; ++i) lst[i] = -3.0e38f;

  const char* fragb = (const char*)memn8;
  for (int tl = 0; tl < S_TILES; ++tl) {
    const size_t grp = (size_t)blockIdx.x * S_TILES + tl;
    const size_t u0 = grp * 8;
    load_lds16(fragb + (u0 + w) * 1024 + l * 16, tile + w * 1024);
    const float* nb = rcpn + grp * 32 + hi4;
    f32x4 n0 = *(const f32x4*)(nb);
    f32x4 n1 = *(const f32x4*)(nb + 8);
    f32x4 n2 = *(const f32x4*)(nb + 16);
    f32x4 n3 = *(const f32x4*)(nb + 24);
    __syncthreads();
    f32x16 acc = {0.f};
#pragma unroll
    for (int g = 0; g < 4; ++g) {
      lx2 a0 = *(const lx2*)(tile + (2 * g) * 1024 + l * 16);
      lx2 a1 = *(const lx2*)(tile + (2 * g + 1) * 1024 + l * 16);
      lx4 aa; aa[0] = a0[0]; aa[1] = a0[1]; aa[2] = a1[0]; aa[3] = a1[1];
      acc = __builtin_amdgcn_mfma_scale_f32_32x32x64_f8f6f4(
          __builtin_bit_cast(i32x8, aa), __builtin_bit_cast(i32x8, zb[g]),
          acc, 0, 0, 0, SCL, 0, SCL);
    }
#pragma unroll
    for (int i = 0; i < 16; ++i) {
      float nv = ((i >> 2) == 0) ? n0[i & 3] : ((i >> 2) == 1) ? n1[i & 3]
                 : ((i >> 2) == 2) ? n2[i & 3] : n3[i & 3];
      topk_insert(lst, acc[i] * nv);
    }
    __syncthreads();
  }

  float mg[16];
#pragma unroll
  for (int r = 0; r < 16; ++r) {
    float h = lst[0];
    float ph = __shfl_xor(h, 32, 64);
    float g = fmaxf(h, ph);
    bool mine = (h > ph) || (h == ph && l < 32);
    if (mine) {
#pragma unroll
      for (int i = 0; i < 15; ++i) lst[i] = lst[i + 1];
      lst[15] = -3.0e38f;
    }
    mg[r] = g;
  }
  if (l < 32) {
    float* dst = tcand + ((size_t)col * S_CHUNKS + blockIdx.x) * 16;
#pragma unroll
    for (int i = 0; i < 16; i += 4) {
      float4 o = make_float4(mg[i], mg[i + 1], mg[i + 2], mg[i + 3]);
      *(float4*)(dst + i) = o;
    }
  }
}

// -------- tau: 16th-largest of the sample candidates (+ zero cnt) -----------
__global__ __launch_bounds__(64) void tau_kernel(
    const float* __restrict__ tcand, float* __restrict__ tau,
    int* __restrict__ cnt) {
  const int b = blockIdx.x;
  const int l = threadIdx.x;
  if (l == 0) cnt[b] = 0;
  float lst[16];
#pragma unroll
  for (int i = 0; i < 16; ++i) lst[i] = -3.0e38f;
  const float* cb = tcand + (size_t)b * (S_CHUNKS * 16);
#pragma unroll
  for (int k = 0; k < (S_CHUNKS * 16) / 64; ++k) topk_insert(lst, cb[k * 64 + l]);

  float g16 = -3.0e38f;
#pragma unroll
  for (int r = 0; r < K_N; ++r) {
    float h = lst[0];
    float g = h;
#pragma unroll
    for (int o = 1; o < 64; o <<= 1) g = fmaxf(g, __shfl_xor(g, o, 64));
    unsigned long long bal = __ballot(h == g);
    int winner = __ffsll(bal) - 1;
    if (l == winner) {
#pragma unroll
      for (int i = 0; i < 15; ++i) lst[i] = lst[i + 1];
      lst[15] = -3.0e38f;
    }
    g16 = g;
  }
  if (l == 0) tau[b] = g16;
}

// ---------------- filter: MX-fp8 GEMM + sim-space threshold stash -----------
// (R20 structure; gate/push on sc = acc*rcpn[row], bitwise same as prepass.)
__global__ __launch_bounds__(256, 4) void filter_kernel(
    const unsigned char* __restrict__ memn8, const unsigned char* __restrict__ z8,
    const float* __restrict__ rcpn, const float* __restrict__ tau,
    int* __restrict__ cnt, float* __restrict__ candv) {
  __shared__ char tile[4 * 8192];  // 4 x 8 KB ring
  const int t = threadIdx.x;
  const int w = t >> 6;
  const int l = t & 63;
  const int c32 = l & 31;
  const int hi4 = (l >> 5) * 4;
  const int bx = blockIdx.x;
  const int col0 = blockIdx.y * 128 + w * 32 + c32;

  lx4 zb[4];  // 32 VGPRs
#pragma unroll
  for (int g = 0; g < 4; ++g)
#pragma unroll
    for (int c = 0; c < 4; ++c)
      zb[g][c] = *(const long*)(z8 + (size_t)col0 * 256 + (4 * g + c) * 16 +
                                (l >> 5) * 8);

  const float tau0 = tau[col0];

  float sA0 = 0.f, sB0 = 0.f, sC0 = 0.f, sD0 = 0.f;
  int n0 = 0;

  char* tileb = (char*)tile;
  const char* fragb = (const char*)memn8;
#define STAGE(buf, tl_)                                                       \
  {                                                                           \
    const char* _g = fragb + ((size_t)(tl_) * 8 + w * 2) * 1024 + l * 16;     \
    char* _d = tileb + (buf) * 8192 + w * 2048;                               \
    load_lds16(_g, _d);                                                       \
    load_lds16(_g + 1024, _d + 1024);                                         \
  }

  STAGE(0, bx)
  STAGE(1, bx + F_NC)
  STAGE(2, bx + 2 * F_NC)
  STAGE(3, bx + 3 * F_NC)   // bx + 384 <= 511 < NT32, valid

  int it = 0;
  for (int tl = bx; tl < NT32; tl += F_NC, ++it) {
    asm volatile("s_waitcnt vmcnt(6)" ::: "memory");
    __builtin_amdgcn_s_barrier();
    __builtin_amdgcn_sched_barrier(0);
#pragma unroll
    for (int g = 0; g < 4; ++g) asm volatile("" : "+v"(zb[g]));
    // per-tile row norms (L2-hot; compiler inserts its own waits; our
    // vmcnt(6) above stays conservative-correct since these retire in-iter)
    const float* nb = rcpn + (size_t)tl * 32 + hi4;
    f32x4 nv0 = *(const f32x4*)(nb);
    f32x4 nv1 = *(const f32x4*)(nb + 8);
    f32x4 nv2 = *(const f32x4*)(nb + 16);
    f32x4 nv3 = *(const f32x4*)(nb + 24);
    const char* curb = tileb + (it & 3) * 8192;
    f32x16 acc0 = {0.f};
#pragma unroll
    for (int g = 0; g < 4; ++g) {
      lx2 a0 = *(const lx2*)(curb + (2 * g) * 1024 + l * 16);
      lx2 a1 = *(const lx2*)(curb + (2 * g + 1) * 1024 + l * 16);
      lx4 aa; aa[0] = a0[0]; aa[1] = a0[1]; aa[2] = a1[0]; aa[3] = a1[1];
      acc0 = __builtin_amdgcn_mfma_scale_f32_32x32x64_f8f6f4(
          __builtin_bit_cast(i32x8, aa), __builtin_bit_cast(i32x8, zb[g]),
          acc0, 0, 0, 0, SCL, 0, SCL);
    }
    {
      float m = -3.0e38f;
#pragma unroll
      for (int i = 0; i < 16; ++i) {
        float nv = ((i >> 2) == 0) ? nv0[i & 3] : ((i >> 2) == 1) ? nv1[i & 3]
                   : ((i >> 2) == 2) ? nv2[i & 3] : nv3[i & 3];
        m = fmaxf(m, acc0[i] * nv);
      }
      if (m >= tau0) {
#pragma unroll
        for (int i = 0; i < 16; ++i) {
          float nv = ((i >> 2) == 0) ? nv0[i & 3] : ((i >> 2) == 1) ? nv1[i & 3]
                     : ((i >> 2) == 2) ? nv2[i & 3] : nv3[i & 3];
          float v = acc0[i] * nv;
          if (v >= tau0) {
            if (n0 == 0) { sA0 = v; n0 = 1; }
            else if (n0 == 1) { sB0 = v; n0 = 2; }
            else if (n0 == 2) { sC0 = v; n0 = 3; }
            else if (n0 == 3) { sD0 = v; n0 = 4; }
            else {
              int p = atomicAdd(&cnt[col0], 1);
              if (p < CAP) candv[(size_t)col0 * CAP + p] = v;
            }
          }
        }
      }
    }
    asm volatile("s_waitcnt lgkmcnt(0)" ::: "memory");
    __builtin_amdgcn_s_barrier();
    int nx = tl + 4 * F_NC;
    if (nx >= NT32) nx = bx;  // dummy stage keeps vmcnt math exact
    STAGE(it & 3, nx)
  }
#undef STAGE

  if (n0 > 0) {
    int p = atomicAdd(&cnt[col0], n0);
    if (p < CAP) candv[(size_t)col0 * CAP + p] = sA0;
    if (n0 > 1 && p + 1 < CAP) candv[(size_t)col0 * CAP + p + 1] = sB0;
    if (n0 > 2 && p + 2 < CAP) candv[(size_t)col0 * CAP + p + 2] = sC0;
    if (n0 > 3 && p + 3 < CAP) candv[(size_t)col0 * CAP + p + 3] = sD0;
  }
}

// ---------------- final: exact top-16 of survivors + combine ----------------
__global__ __launch_bounds__(64) void final_kernel(
    const int* __restrict__ cnt, const float* __restrict__ candv,
    float* __restrict__ out) {
  const int b = blockIdx.x;
  const int l = threadIdx.x;
  const int n = min(cnt[b], CAP);
  float lst[16];
#pragma unroll
  for (int i = 0; i < 16; ++i) lst[i] = -3.0e38f;
  const float* cb = candv + (size_t)b * CAP;
  for (int k = l; k < n; k += 64) topk_insert(lst, cb[k]);

  float sum = 0.0f;
#pragma unroll
  for (int r = 0; r < K_N; ++r) {
    float h = lst[0];
    float g = h;
#pragma unroll
    for (int o = 1; o < 64; o <<= 1) g = fmaxf(g, __shfl_xor(g, o, 64));
    unsigned long long bal = __ballot(h == g);
    int winner = __ffsll(bal) - 1;
    if (l == winner) {
#pragma unroll
      for (int i = 0; i < 15; ++i) lst[i] = lst[i + 1];
      lst[15] = -3.0e38f;
    }
    sum += g;
  }
  float nov = 1.0f - sum / (float)K_N;
  nov = fminf(fmaxf(nov, 0.0f), 1.0f);
  if (l == 0) {
    float pe = out[B_N + b];
    float ep = out[2 * B_N + b];
    out[b] = pe + 0.5f * ep + 0.5f * nov;
    out[3 * B_N + b] = nov;
  }
}

extern "C" void kernel_launch(void* const* d_in, const int* in_sizes, int n_in,
                              void* d_out, int out_size, void* d_ws, size_t ws_size,
                              hipStream_t stream) {
  (void)in_sizes; (void)n_in; (void)out_size; (void)ws_size;
  const float* z_t    = (const float*)d_in[0];
  const float* action = (const float*)d_in[1];
  const float* z_t1   = (const float*)d_in[2];
  const float* sigma  = (const float*)d_in[3];
  const float* mem    = (const float*)d_in[4];
  const float* W1 = (const float*)d_in[5];
  const float* b1 = (const float*)d_in[6];
  const float* g1 = (const float*)d_in[7];
  const float* be1= (const float*)d_in[8];
  const float* W2 = (const float*)d_in[9];
  const float* b2 = (const float*)d_in[10];
  const float* g2 = (const float*)d_in[11];
  const float* be2= (const float*)d_in[12];
  const float* W3 = (const float*)d_in[13];
  const float* b3 = (const float*)d_in[14];
  float* out = (float*)d_out;

  char* ws = (char*)d_ws;
  unsigned char* memn8 = (unsigned char*)ws;            // 51,200,000 B (fp8 units)
  unsigned char* z8    = (unsigned char*)(ws + 51200000);   // 262,144 B
  float*  tcand = (float*)(ws + 51462144);              // 4,194,304 B
  float*  tau   = (float*)(ws + 55656448);              // 4,096 B
  int*    cnt   = (int*)(ws + 55660544);                // 4,096 B
  float*  candv = (float*)(ws + 55664640);              // 4,194,304 B
  float*  rcpn  = (float*)(ws + 59858944);              // 800,000 B

  prep_kernel<<<B_N + NT32, 256, 0, stream>>>(
      mem, memn8, z_t, action, z_t1, sigma,
      W1, b1, g1, be1, W2, b2, g2, be2, W3, b3, out, z8);
  norm_kernel<<<NT32, 256, 0, stream>>>(memn8, rcpn);
  prepass_kernel<<<dim3(S_CHUNKS, 4), 512, 0, stream>>>(memn8, z8, rcpn, tcand);
  tau_kernel<<<B_N, 64, 0, stream>>>(tcand, tau, cnt);
  filter_kernel<<<dim3(F_NC, F_BY), 256, 0, stream>>>(memn8, z8, rcpn, tau, cnt, candv);
  final_kernel<<<B_N, 64, 0, stream>>>(cnt, candv, out);
}

// Round 25
// 203.875 us; speedup vs baseline: 1.1224x; 1.1224x over previous
//
#include <hip/hip_runtime.h>
#include <hip/hip_bf16.h>

typedef float f32x4 __attribute__((ext_vector_type(4)));
typedef float f32x16 __attribute__((ext_vector_type(16)));
typedef long lx2 __attribute__((ext_vector_type(2)));
typedef long lx4 __attribute__((ext_vector_type(4)));
typedef int i32x8 __attribute__((ext_vector_type(8)));

#define B_N 1024
#define D_N 256
#define A_N 6
#define M_N 200000
#define K_N 16
#define H1_N 128
#define H2_N 64
#define NT32 6250       // 200000 / 32 (32-row tiles)
#define S_TILES 6       // prepass tiles per chunk (32-row tiles)
#define S_CHUNKS 64     // sample = 64*6*32 = 12288 rows
#define F_NC 128        // filter: m-chunk count (grid.x)
#define F_BY 8          // filter: b-groups of 128 cols -> 1024 blocks = 4/CU
#define CAP 1024        // per-b survivor capacity
#define MEMCVT_BLKS NT32  // 6250 blocks x 32 rows
#define SCL 0x7F7F7F7F  // E8M0 scale bytes = 127 -> 2^0 = 1.0 (unit scale)

// memn8 (fp8 e4m3, row-normalized) is stored in 32x32-MFMA A-fragment UNITS:
// unit u of 32-row group g covers rows g*32..+31, cols u*32..+31 (1024 B).
// byte l*16 + h*8 + j = element (row = l&31, k_local = h*16 + (l>>5)*8 + j).
// K=64 MX operand = [unit 2g (16B/lane) | unit 2g+1 (16B/lane)]; the z pack
// uses the identical per-lane k-order, so A/B byte i pair on the same k.

__device__ __forceinline__ float wred_sum(float v) {
#pragma unroll
  for (int o = 1; o < 64; o <<= 1) v += __shfl_xor(v, o, 64);
  return v;
}

__device__ __forceinline__ void topk_insert(float (&lst)[16], float v) {
  if (v <= lst[15]) return;
#pragma unroll
  for (int i = 0; i < 16; ++i) {
    bool gt = v > lst[i];
    float hi = gt ? v : lst[i];
    v = gt ? lst[i] : v;
    lst[i] = hi;
  }
}

__device__ __forceinline__ void load_lds16(const void* g, void* l) {
  __builtin_amdgcn_global_load_lds(
      (const __attribute__((address_space(1))) unsigned int*)g,
      (__attribute__((address_space(3))) unsigned int*)l, 16, 0, 0);
}

__device__ __forceinline__ int cvt2fp8(float a, float b) {
  return __builtin_amdgcn_cvt_pk_fp8_f32(a, b, 0, false);  // low 2 bytes
}

// ---------- fused: forward model (blocks 0..1023) + memcvt (blocks 1024+) ---
// (R20 configuration -- measured best, 205.3 us total. prep's ~116 us is
// dominated by the harness poison-fill's 800 MB HBM writeback draining while
// prep does its cold 204.8 MB read: external, structure-invariant.)
__global__ __launch_bounds__(256) void prep_kernel(
    const float* __restrict__ mem, unsigned char* __restrict__ memn8,
    const float* __restrict__ z_t, const float* __restrict__ action,
    const float* __restrict__ z_t1, const float* __restrict__ sigma,
    const float* __restrict__ W1, const float* __restrict__ b1,
    const float* __restrict__ g1, const float* __restrict__ be1,
    const float* __restrict__ W2, const float* __restrict__ b2,
    const float* __restrict__ g2, const float* __restrict__ be2,
    const float* __restrict__ W3, const float* __restrict__ b3,
    float* __restrict__ out, unsigned char* __restrict__ z8) {
  __shared__ float s_inp[D_N + A_N];
  __shared__ float s_h1[H1_N];
  __shared__ float s_h2[H2_N];
  __shared__ float red[8];
  __shared__ char s8[32 * 264];  // 32 fp8 rows, 264 B pitch (bank rotate)
  const int t = threadIdx.x;
  const int w = t >> 6;
  const int l = t & 63;

  if (blockIdx.x >= B_N) {
    const int g32 = blockIdx.x - B_N;
#pragma unroll
    for (int i = 0; i < 8; ++i) {
      const int r = i * 4 + w;  // 0..31, wave-uniform
      const f32x4 v =
          *(const f32x4*)(mem + ((size_t)g32 * 32 + r) * D_N + l * 4);
      float ss = v[0]*v[0] + v[1]*v[1] + v[2]*v[2] + v[3]*v[3];
      ss = wred_sum(ss);
      const float inv = 1.0f / (sqrtf(ss) + 1e-8f);
      int p01 = cvt2fp8(v[0] * inv, v[1] * inv);
      int p23 = cvt2fp8(v[2] * inv, v[3] * inv);
      unsigned int four = (p01 & 0xffff) | ((unsigned)(p23 & 0xffff) << 16);
      *(unsigned int*)(s8 + r * 264 + l * 4) = four;
    }
    __syncthreads();
    char* dstb = (char*)memn8 + (size_t)g32 * 8192;  // 8 units x 1024 B
#pragma unroll
    for (int uu = 0; uu < 2; ++uu) {
      const int u = w * 2 + uu;  // wave-uniform unit
      const int koff = u * 32 + (l >> 5) * 8;
      long lo = *(const long*)(s8 + (l & 31) * 264 + koff);
      long hi = *(const long*)(s8 + (l & 31) * 264 + koff + 16);
      lx2 o; o[0] = lo; o[1] = hi;
      *(lx2*)(dstb + u * 1024 + l * 16) = o;
    }
    return;
  }

  // ---- forward model for sample b ----
  const int bb = blockIdx.x;

  float zv = z_t[bb * D_N + t];
  s_inp[t] = zv;
  if (t < A_N) s_inp[D_N + t] = action[bb * A_N + t];

  float ss = wred_sum(zv * zv);
  if ((t & 63) == 0) red[w] = ss;
  __syncthreads();
  float tot = red[0] + red[1] + red[2] + red[3];
  float invz = 1.0f / (sqrtf(tot) + 1e-8f);
  if (t < 128) {
    int pk = cvt2fp8(s_inp[2 * t] * invz, s_inp[2 * t + 1] * invz);
    *(unsigned short*)(z8 + (size_t)bb * 256 + 2 * t) =
        (unsigned short)(pk & 0xffff);
  }

  float y1 = 0.0f;
  if (t < H1_N) {
    y1 = b1[t];
    for (int k = 0; k < D_N + A_N; ++k) y1 += s_inp[k] * W1[k * H1_N + t];
  }
  __syncthreads();
  float s1 = wred_sum(t < H1_N ? y1 : 0.0f);
  float q1 = wred_sum(t < H1_N ? y1 * y1 : 0.0f);
  if ((t & 63) == 0) { red[w] = s1; red[4 + w] = q1; }
  __syncthreads();
  float S1 = red[0] + red[1] + red[2] + red[3];
  float Q1 = red[4] + red[5] + red[6] + red[7];
  float mu1 = S1 / (float)H1_N;
  float var1 = Q1 / (float)H1_N - mu1 * mu1;
  float rs1 = rsqrtf(var1 + 1e-5f);
  if (t < H1_N) {
    float xn = (y1 - mu1) * rs1;
    s_h1[t] = fmaxf(0.0f, xn * g1[t] + be1[t]);
  }
  __syncthreads();

  float y2 = 0.0f;
  if (t < H2_N) {
    y2 = b2[t];
    for (int k = 0; k < H1_N; ++k) y2 += s_h1[k] * W2[k * H2_N + t];
  }
  __syncthreads();
  float s2 = wred_sum(t < H2_N ? y2 : 0.0f);
  float q2 = wred_sum(t < H2_N ? y2 * y2 : 0.0f);
  if ((t & 63) == 0) { red[w] = s2; red[4 + w] = q2; }
  __syncthreads();
  float S2 = red[0] + red[1] + red[2] + red[3];
  float Q2 = red[4] + red[5] + red[6] + red[7];
  float mu2 = S2 / (float)H2_N;
  float var2 = Q2 / (float)H2_N - mu2 * mu2;
  float rs2 = rsqrtf(var2 + 1e-5f);
  if (t < H2_N) {
    float xn = (y2 - mu2) * rs2;
    s_h2[t] = fmaxf(0.0f, xn * g2[t] + be2[t]);
  }
  __syncthreads();

  float zp = b3[t];
  for (int k = 0; k < H2_N; ++k) zp += s_h2[k] * W3[k * D_N + t];
  float d = zp - z_t1[bb * D_N + t];
  __syncthreads();
  float pe = wred_sum(d * d);
  if ((t & 63) == 0) red[w] = pe;
  __syncthreads();
  if (t == 0) {
    float PE = (red[0] + red[1] + red[2] + red[3]) / (float)D_N;
    out[B_N + bb] = PE;
    float s6 = 0.0f;
    for (int i = 0; i < A_N; ++i) s6 += sigma[bb * A_N + i];
    out[2 * B_N + bb] = s6 / (float)A_N;
  }
}

// ---------------- prepass: exact MX-fp8 top-16 over 12288-row sample --------
// Same scaled-MFMA, single acc chain as filter -> bitwise-identical sims.
__global__ __launch_bounds__(512) void prepass_kernel(
    const unsigned char* __restrict__ memn8, const unsigned char* __restrict__ z8,
    float* __restrict__ tcand) {
  __shared__ char tile[8192];  // 8 units x 1024 B
  const int t = threadIdx.x;
  const int w = t >> 6;       // 0..7
  const int l = t & 63;
  const int c32 = l & 31;
  const int col = blockIdx.y * 256 + w * 32 + c32;

  lx4 zb[4];  // 32 VGPRs: K64-group g = 4 x 8B chunks, k-order matches A
#pragma unroll
  for (int g = 0; g < 4; ++g)
#pragma unroll
    for (int c = 0; c < 4; ++c)
      zb[g][c] = *(const long*)(z8 + (size_t)col * 256 + (4 * g + c) * 16 +
                                (l >> 5) * 8);

  float lst[16];
#pragma unroll
  for (int i = 0; i < 16; ++i) lst[i] = -3.0e38f;

  const char* fragb = (const char*)memn8;
  for (int tl = 0; tl < S_TILES; ++tl) {
    const size_t u0 = ((size_t)blockIdx.x * S_TILES + tl) * 8;
    load_lds16(fragb + (u0 + w) * 1024 + l * 16, tile + w * 1024);
    __syncthreads();
    f32x16 acc = {0.f};
#pragma unroll
    for (int g = 0; g < 4; ++g) {
      lx2 a0 = *(const lx2*)(tile + (2 * g) * 1024 + l * 16);
      lx2 a1 = *(const lx2*)(tile + (2 * g + 1) * 1024 + l * 16);
      lx4 aa; aa[0] = a0[0]; aa[1] = a0[1]; aa[2] = a1[0]; aa[3] = a1[1];
      acc = __builtin_amdgcn_mfma_scale_f32_32x32x64_f8f6f4(
          __builtin_bit_cast(i32x8, aa), __builtin_bit_cast(i32x8, zb[g]),
          acc, 0, 0, 0, SCL, 0, SCL);
    }
#pragma unroll
    for (int i = 0; i < 16; ++i) topk_insert(lst, acc[i]);
    __syncthreads();
  }

  float mg[16];
#pragma unroll
  for (int r = 0; r < 16; ++r) {
    float h = lst[0];
    float ph = __shfl_xor(h, 32, 64);
    float g = fmaxf(h, ph);
    bool mine = (h > ph) || (h == ph && l < 32);
    if (mine) {
#pragma unroll
      for (int i = 0; i < 15; ++i) lst[i] = lst[i + 1];
      lst[15] = -3.0e38f;
    }
    mg[r] = g;
  }
  if (l < 32) {
    float* dst = tcand + ((size_t)col * S_CHUNKS + blockIdx.x) * 16;
#pragma unroll
    for (int i = 0; i < 16; i += 4) {
      float4 o = make_float4(mg[i], mg[i + 1], mg[i + 2], mg[i + 3]);
      *(float4*)(dst + i) = o;
    }
  }
}

// -------- tau: 16th-largest of the sample candidates (+ zero cnt) -----------
__global__ __launch_bounds__(64) void tau_kernel(
    const float* __restrict__ tcand, float* __restrict__ tau,
    int* __restrict__ cnt) {
  const int b = blockIdx.x;
  const int l = threadIdx.x;
  if (l == 0) cnt[b] = 0;
  float lst[16];
#pragma unroll
  for (int i = 0; i < 16; ++i) lst[i] = -3.0e38f;
  const float* cb = tcand + (size_t)b * (S_CHUNKS * 16);
#pragma unroll
  for (int k = 0; k < (S_CHUNKS * 16) / 64; ++k) topk_insert(lst, cb[k * 64 + l]);

  float g16 = -3.0e38f;
#pragma unroll
  for (int r = 0; r < K_N; ++r) {
    float h = lst[0];
    float g = h;
#pragma unroll
    for (int o = 1; o < 64; o <<= 1) g = fmaxf(g, __shfl_xor(g, o, 64));
    unsigned long long bal = __ballot(h == g);
    int winner = __ffsll(bal) - 1;
    if (l == winner) {
#pragma unroll
      for (int i = 0; i < 15; ++i) lst[i] = lst[i + 1];
      lst[15] = -3.0e38f;
    }
    g16 = g;
  }
  if (l == 0) tau[b] = g16;
}

// ---------------- filter: MX-fp8 32x32x64 GEMM + threshold stash ------------
// R19 structure (4 co-resident barrier groups/CU, FETCH-preserving) with the
// MFMA pipe halved: 4 scaled MFMAs per tile (K=64 each, 2.14x rate).
__global__ __launch_bounds__(256, 4) void filter_kernel(
    const unsigned char* __restrict__ memn8, const unsigned char* __restrict__ z8,
    const float* __restrict__ tau, int* __restrict__ cnt,
    float* __restrict__ candv) {
  __shared__ char tile[4 * 8192];  // 4 x 8 KB ring
  const int t = threadIdx.x;
  const int w = t >> 6;
  const int l = t & 63;
  const int c32 = l & 31;
  const int bx = blockIdx.x;
  const int col0 = blockIdx.y * 128 + w * 32 + c32;

  lx4 zb[4];  // 32 VGPRs
#pragma unroll
  for (int g = 0; g < 4; ++g)
#pragma unroll
    for (int c = 0; c < 4; ++c)
      zb[g][c] = *(const long*)(z8 + (size_t)col0 * 256 + (4 * g + c) * 16 +
                                (l >> 5) * 8);

  const float tau0 = tau[col0];

  float sA0 = 0.f, sB0 = 0.f, sC0 = 0.f, sD0 = 0.f;
  int n0 = 0;

  char* tileb = (char*)tile;
  const char* fragb = (const char*)memn8;
#define STAGE(buf, tl_)                                                       \
  {                                                                           \
    const char* _g = fragb + ((size_t)(tl_) * 8 + w * 2) * 1024 + l * 16;     \
    char* _d = tileb + (buf) * 8192 + w * 2048;                               \
    load_lds16(_g, _d);                                                       \
    load_lds16(_g + 1024, _d + 1024);                                         \
  }

  STAGE(0, bx)
  STAGE(1, bx + F_NC)
  STAGE(2, bx + 2 * F_NC)
  STAGE(3, bx + 3 * F_NC)   // bx + 384 <= 511 < NT32, valid

  int it = 0;
  for (int tl = bx; tl < NT32; tl += F_NC, ++it) {
    asm volatile("s_waitcnt vmcnt(6)" ::: "memory");
    __builtin_amdgcn_s_barrier();
    __builtin_amdgcn_sched_barrier(0);
#pragma unroll
    for (int g = 0; g < 4; ++g) asm volatile("" : "+v"(zb[g]));
    const char* curb = tileb + (it & 3) * 8192;
    f32x16 acc0 = {0.f};
#pragma unroll
    for (int g = 0; g < 4; ++g) {
      lx2 a0 = *(const lx2*)(curb + (2 * g) * 1024 + l * 16);
      lx2 a1 = *(const lx2*)(curb + (2 * g + 1) * 1024 + l * 16);
      lx4 aa; aa[0] = a0[0]; aa[1] = a0[1]; aa[2] = a1[0]; aa[3] = a1[1];
      acc0 = __builtin_amdgcn_mfma_scale_f32_32x32x64_f8f6f4(
          __builtin_bit_cast(i32x8, aa), __builtin_bit_cast(i32x8, zb[g]),
          acc0, 0, 0, 0, SCL, 0, SCL);
    }
    {
      float m = acc0[0];
#pragma unroll
      for (int i = 1; i < 16; ++i) m = fmaxf(m, acc0[i]);
      if (m >= tau0) {
#pragma unroll
        for (int i = 0; i < 16; ++i) {
          float v = acc0[i];
          if (v >= tau0) {
            if (n0 == 0) { sA0 = v; n0 = 1; }
            else if (n0 == 1) { sB0 = v; n0 = 2; }
            else if (n0 == 2) { sC0 = v; n0 = 3; }
            else if (n0 == 3) { sD0 = v; n0 = 4; }
            else {
              int p = atomicAdd(&cnt[col0], 1);
              if (p < CAP) candv[(size_t)col0 * CAP + p] = v;
            }
          }
        }
      }
    }
    asm volatile("s_waitcnt lgkmcnt(0)" ::: "memory");
    __builtin_amdgcn_s_barrier();
    int nx = tl + 4 * F_NC;
    if (nx >= NT32) nx = bx;  // dummy stage keeps vmcnt math exact
    STAGE(it & 3, nx)
  }
#undef STAGE

  if (n0 > 0) {
    int p = atomicAdd(&cnt[col0], n0);
    if (p < CAP) candv[(size_t)col0 * CAP + p] = sA0;
    if (n0 > 1 && p + 1 < CAP) candv[(size_t)col0 * CAP + p + 1] = sB0;
    if (n0 > 2 && p + 2 < CAP) candv[(size_t)col0 * CAP + p + 2] = sC0;
    if (n0 > 3 && p + 3 < CAP) candv[(size_t)col0 * CAP + p + 3] = sD0;
  }
}

// ---------------- final: exact top-16 of survivors + combine ----------------
__global__ __launch_bounds__(64) void final_kernel(
    const int* __restrict__ cnt, const float* __restrict__ candv,
    float* __restrict__ out) {
  const int b = blockIdx.x;
  const int l = threadIdx.x;
  const int n = min(cnt[b], CAP);
  float lst[16];
#pragma unroll
  for (int i = 0; i < 16; ++i) lst[i] = -3.0e38f;
  const float* cb = candv + (size_t)b * CAP;
  for (int k = l; k < n; k += 64) topk_insert(lst, cb[k]);

  float sum = 0.0f;
#pragma unroll
  for (int r = 0; r < K_N; ++r) {
    float h = lst[0];
    float g = h;
#pragma unroll
    for (int o = 1; o < 64; o <<= 1) g = fmaxf(g, __shfl_xor(g, o, 64));
    unsigned long long bal = __ballot(h == g);
    int winner = __ffsll(bal) - 1;
    if (l == winner) {
#pragma unroll
      for (int i = 0; i < 15; ++i) lst[i] = lst[i + 1];
      lst[15] = -3.0e38f;
    }
    sum += g;
  }
  float nov = 1.0f - sum / (float)K_N;
  nov = fminf(fmaxf(nov, 0.0f), 1.0f);
  if (l == 0) {
    float pe = out[B_N + b];
    float ep = out[2 * B_N + b];
    out[b] = pe + 0.5f * ep + 0.5f * nov;
    out[3 * B_N + b] = nov;
  }
}

extern "C" void kernel_launch(void* const* d_in, const int* in_sizes, int n_in,
                              void* d_out, int out_size, void* d_ws, size_t ws_size,
                              hipStream_t stream) {
  (void)in_sizes; (void)n_in; (void)out_size; (void)ws_size;
  const float* z_t    = (const float*)d_in[0];
  const float* action = (const float*)d_in[1];
  const float* z_t1   = (const float*)d_in[2];
  const float* sigma  = (const float*)d_in[3];
  const float* mem    = (const float*)d_in[4];
  const float* W1 = (const float*)d_in[5];
  const float* b1 = (const float*)d_in[6];
  const float* g1 = (const float*)d_in[7];
  const float* be1= (const float*)d_in[8];
  const float* W2 = (const float*)d_in[9];
  const float* b2 = (const float*)d_in[10];
  const float* g2 = (const float*)d_in[11];
  const float* be2= (const float*)d_in[12];
  const float* W3 = (const float*)d_in[13];
  const float* b3 = (const float*)d_in[14];
  float* out = (float*)d_out;

  char* ws = (char*)d_ws;
  unsigned char* memn8 = (unsigned char*)ws;            // 51,200,000 B (fp8 units)
  unsigned char* z8    = (unsigned char*)(ws + 51200000);   // 262,144 B
  float*  tcand = (float*)(ws + 51462144);              // 4,194,304 B
  float*  tau   = (float*)(ws + 55656448);              // 4,096 B
  int*    cnt   = (int*)(ws + 55660544);                // 4,096 B
  float*  candv = (float*)(ws + 55664640);              // 4,194,304 B

  prep_kernel<<<B_N + MEMCVT_BLKS, 256, 0, stream>>>(
      mem, memn8, z_t, action, z_t1, sigma,
      W1, b1, g1, be1, W2, b2, g2, be2, W3, b3, out, z8);
  prepass_kernel<<<dim3(S_CHUNKS, 4), 512, 0, stream>>>(memn8, z8, tcand);
  tau_kernel<<<B_N, 64, 0, stream>>>(tcand, tau, cnt);
  filter_kernel<<<dim3(F_NC, F_BY), 256, 0, stream>>>(memn8, z8, tau, cnt, candv);
  final_kernel<<<B_N, 64, 0, stream>>>(cnt, candv, out);
}